// Round 16
// baseline (130.841 us; speedup 1.0000x reference)
//
#include <hip/hip_runtime.h>

#define PI_F 3.14159265358979323846f

// Problem constants: B=4, Cin=Cout=64, H=W=128, Wf=65, K=3
#define HH 128
#define WW 128
#define WF 65
#define NB 4
#define NC 64
#define CPLX_PER_IMG (HH * WF)                  // 8320

typedef __attribute__((ext_vector_type(8))) short short8;
typedef __attribute__((ext_vector_type(4))) float f32x4;

__device__ __forceinline__ ushort f2b(float f) {   // f32 -> bf16 RNE
    unsigned u = __float_as_uint(f);
    u += 0x7fffu + ((u >> 16) & 1u);
    return (ushort)(u >> 16);
}

// ===================== ws layout (bytes) =====================
// ctr @ 0 (4) | A4: [256][256] @ 172032 | A5: [128][160] @ 303104
// WvRe/WvIm @ 344064/1941504 (2x 1597440)
// XsRe/XsIm @ 12058624/16318464 (2x 4259840) | Zre/Zim @ 20578304/24838144

// ---------------- graft item: Wv planes + A4 + A5 (idx in [86016, 970752)) -------------
__device__ __forceinline__ void pre_item_tail(int idx, const float* __restrict__ w,
                                              ushort* __restrict__ A4,
                                              ushort* __restrict__ A5,
                                              ushort* __restrict__ WvRe,
                                              ushort* __restrict__ WvIm) {
    if (idx < 151552) {                      // A4[m][k2]: inv col DFT, /128
        int j = idx - 86016;
        int m = j >> 8, k2 = j & 255;
        int part = m >> 7, h = m & 127;
        int kp = k2 >> 7, u = k2 & 127;
        float s, c;
        __sincosf(2.f * PI_F * (float)((u * h) & 127) / 128.f, &s, &c);
        float val = part == 0 ? (kp == 0 ? c : -s) : (kp == 0 ? s : c);
        A4[j] = f2b(val * (1.f / 128.f));
    } else if (idx < 172032) {               // A5[x][k2]: c2r, /128
        int j = idx - 151552;
        int x = j / 160, k2 = j - x * 160;
        int part = k2 / 80, v = k2 - part * 80;
        float s, c;
        __sincosf(2.f * PI_F * (float)((v * x) & 127) / 128.f, &s, &c);
        float cv = (v == 0 || v == 64) ? 1.f : 2.f;
        float val = (v < 65) ? (part == 0 ? cv * c : -cv * s) * (1.f / 128.f) : 0.f;
        A5[j] = f2b(val);
    } else {                                 // Wv[p][v][o][i]
        int xw = idx - 172032;               // 0..798719
        int i = xw & 63;
        int o = (xw >> 6) & 63;
        int pv = xw >> 12;
        int p = pv / WF;
        int v = pv % WF;
        const float* wp = w + ((size_t)o * 64 + i) * 9 + p * 3;
        float re = wp[0], im = 0.f;
#pragma unroll
        for (int q = 1; q <= 2; ++q) {
            int k = (v * q) & 127;
            float s, c;
            __sincosf(-2.f * PI_F * (float)k / 128.f, &s, &c);
            re += wp[q] * c;
            im += wp[q] * s;
        }
        WvRe[xw] = f2b(re);
        WvIm[xw] = f2b(im);
    }
}

// ---------------- k_fwd: R15-identical + ctr zeroing ----------
#define B2P 280
#define A1P 136
__global__ __launch_bounds__(1024) void k_fwd(const float* __restrict__ x,
                                              const float* __restrict__ w,
                                              ushort* __restrict__ XsRe,
                                              ushort* __restrict__ XsIm,
                                              ushort* __restrict__ WvRe,
                                              ushort* __restrict__ WvIm,
                                              ushort* __restrict__ A4,
                                              ushort* __restrict__ A5,
                                              unsigned int* __restrict__ ctr) {
    __shared__ ushort A1L[160 * A1P];        // 42.5 KB
    __shared__ ushort B2[80 * B2P];          // 44.8 KB
    __shared__ __align__(16) float2 TW[128]; // e^{+2pi i k/128}
    int t = threadIdx.x;
    int img = blockIdx.x;
    const float* gx = x + (size_t)img * 16384;

    if (img == 0 && t == 0) *ctr = 0;        // barrier counter for k_mi (visible at launch boundary)

    // ---- phase 0: A1L gen || TW gen || graft ----
    if (t < 128) {
        float s, c;
        __sincosf(2.f * PI_F * (float)t / 128.f, &s, &c);
        TW[t] = make_float2(c, s);
    }
    for (int idx = t; idx < 20480; idx += 1024) {
        int m = idx >> 7, k = idx & 127;
        int part = m / 80, v = m - part * 80;
        float s, c;
        __sincosf(2.f * PI_F * (float)((v * k) & 127) / 128.f, &s, &c);
        float val = (v < 65) ? (part ? -s : c) : 0.f;
        A1L[m * A1P + k] = f2b(val);
    }
    {
        int gtid = img * 1024 + t;           // [0, 262144)
        for (int idx = 86016 + gtid; idx < 970752; idx += 262144)
            pre_item_tail(idx, w, A4, A5, WvRe, WvIm);
    }
    __syncthreads();

    int lane = t & 63, wave = t >> 6;        // wave 0..15
    int lrow = lane & 15, lq = lane >> 4;

    // ---- S1: C[m=(part,v)][n=h]; B-frag direct from global x ----
    {
        int g = wave >> 3, nt = wave & 7;
        int hrow = nt * 16 + lrow;
        f32x4 acc[5];
#pragma unroll
        for (int j = 0; j < 5; ++j) acc[j] = (f32x4){0.f, 0.f, 0.f, 0.f};
#pragma unroll
        for (int ks = 0; ks < 4; ++ks) {
            const float* xp = gx + hrow * 128 + ks * 32 + lq * 8;
            float4 f0 = *(const float4*)xp;
            float4 f1 = *(const float4*)(xp + 4);
            short8 b;
            b[0] = (short)f2b(f0.x); b[1] = (short)f2b(f0.y);
            b[2] = (short)f2b(f0.z); b[3] = (short)f2b(f0.w);
            b[4] = (short)f2b(f1.x); b[5] = (short)f2b(f1.y);
            b[6] = (short)f2b(f1.z); b[7] = (short)f2b(f1.w);
#pragma unroll
            for (int j = 0; j < 5; ++j) {
                int mt = g * 5 + j;
                short8 a = *(const short8*)&A1L[(mt * 16 + lrow) * A1P + ks * 32 + lq * 8];
                acc[j] = __builtin_amdgcn_mfma_f32_16x16x32_bf16(a, b, acc[j], 0, 0, 0);
            }
        }
#pragma unroll
        for (int j = 0; j < 5; ++j) {
            int m0 = (g * 5 + j) * 16 + lq * 4;
            int part = m0 >= 80;
            int v0 = m0 - part * 80;
#pragma unroll
            for (int e = 0; e < 4; ++e)
                B2[(v0 + e) * B2P + part * 128 + hrow] = f2b(acc[j][e]);
        }
    }
    __syncthreads();

    // ---- S2 (swapped): C[m=v][n=(part,u)]; B-frags from TW ----
    {
        int nt = wave;
        int part = nt >= 8;
        int um = (nt & 7) * 16 + lrow;
        f32x4 acc[5];
#pragma unroll
        for (int mt = 0; mt < 5; ++mt) acc[mt] = (f32x4){0.f, 0.f, 0.f, 0.f};
#pragma unroll
        for (int ks = 0; ks < 8; ++ks) {
            int kp = ks >> 2;
            int hbase = (ks & 3) * 32 + lq * 8;
            short8 bfr;
            int idx = (um * hbase) & 127;
#pragma unroll
            for (int e = 0; e < 8; ++e) {
                float2 tw = TW[idx];
                float val = !part ? (kp == 0 ? tw.x : tw.y)
                                  : (kp == 0 ? -tw.y : tw.x);
                bfr[e] = (short)f2b(val);
                idx = (idx + um) & 127;
            }
#pragma unroll
            for (int mt = 0; mt < 5; ++mt) {
                short8 a = *(short8*)&B2[(mt * 16 + lrow) * B2P + ks * 32 + lq * 8];
                acc[mt] = __builtin_amdgcn_mfma_f32_16x16x32_bf16(a, bfr, acc[mt], 0, 0, 0);
            }
        }
        int u = (nt & 7) * 16 + lrow;
        int u_out = (u + 64) & 127;
        int du = u_out - 64;
        ushort* dimg = (part ? XsIm : XsRe) + (size_t)img * CPLX_PER_IMG;
#pragma unroll
        for (int mt = 0; mt < 5; ++mt)
#pragma unroll
            for (int e = 0; e < 4; ++e) {
                int v_in = mt * 16 + lq * 4 + e;
                if (v_in < 65) {
                    int v_out = v_in + 32; if (v_out >= 65) v_out -= 65;
                    int dv = v_out - 64;
                    bool keep = (du * du + dv * dv) > 900;
                    dimg[v_out * 128 + u_out] = keep ? f2b(acc[mt][e]) : (ushort)0;
                }
            }
    }
}

// ---------------- k_mi: gemm phase (R9 P2) + manual grid barrier + inv phase ----------
// grid 256, 1024 threads. LDS pool 87.8 KB -> exactly 1 block/CU -> all co-resident.
#define AP  72
#define B3P 168
__global__ __launch_bounds__(1024) void k_mi(const ushort* __restrict__ XsRe,
                                             const ushort* __restrict__ XsIm,
                                             const ushort* __restrict__ WvRe,
                                             const ushort* __restrict__ WvIm,
                                             ushort* __restrict__ Zre,
                                             ushort* __restrict__ Zim,
                                             const ushort* __restrict__ A4,
                                             const ushort* __restrict__ A5,
                                             const float* __restrict__ bias,
                                             float* __restrict__ out,
                                             unsigned int* __restrict__ ctr) {
    __shared__ __align__(16) ushort POOL[43904];   // 87.8 KB, aliased per phase
    int t = threadIdx.x;
    int bid = blockIdx.x;
    int lane = t & 63, wave = t >> 6;        // wave 0..15
    int lrow = lane & 15, lq = lane >> 4;

    // ================= phase A: per-(v,b) complex GEMM + phase fold =================
    {
        ushort* XTre = POOL;                      // [128][AP]
        ushort* XTim = POOL + 128 * AP;
        ushort* WSre = POOL + 2 * 128 * AP;       // [64][AP]
        ushort* WSim = POOL + 2 * 128 * AP + 64 * AP;
        for (int tile = bid; tile < 260; tile += 256) {
            int v = tile >> 2, b = tile & 3;
            __syncthreads();                      // protect LDS from previous tile readers
            {   // stage X transposed [u][i], both planes
                int u = t & 127, q = t >> 7;      // q 0..7 -> i octet
                const ushort* bR = XsRe + ((size_t)(b * 64 + q * 8) * WF + v) * 128 + u;
                const ushort* bI = XsIm + ((size_t)(b * 64 + q * 8) * WF + v) * 128 + u;
                short8 vr, vi;
#pragma unroll
                for (int c = 0; c < 8; ++c) {
                    vr[c] = (short)bR[(size_t)c * WF * 128];
                    vi[c] = (short)bI[(size_t)c * WF * 128];
                }
                *(short8*)&XTre[u * AP + q * 8] = vr;
                *(short8*)&XTim[u * AP + q * 8] = vi;
            }
            int uq = wave >> 2, ot = wave & 3;
            int u0 = uq * 32;
            f32x4 fRe[2], fIm[2];
#pragma unroll
            for (int m = 0; m < 2; ++m) {
                fRe[m] = (f32x4){0.f, 0.f, 0.f, 0.f};
                fIm[m] = (f32x4){0.f, 0.f, 0.f, 0.f};
            }
            for (int p = 0; p < 3; ++p) {
                __syncthreads();                  // XT ready (p==0) / WS readers done (p>0)
                {
                    const ushort* gr = WvRe + ((size_t)(p * WF + v)) * 4096;
                    const ushort* gi = WvIm + ((size_t)(p * WF + v)) * 4096;
                    if (t < 512) {
                        int o = t >> 3, i0 = (t & 7) * 8;
                        *(short8*)&WSre[o * AP + i0] = *(const short8*)&gr[t * 8];
                    } else {
                        int c = t - 512;
                        int o = c >> 3, i0 = (c & 7) * 8;
                        *(short8*)&WSim[o * AP + i0] = *(const short8*)&gi[c * 8];
                    }
                }
                __syncthreads();
                f32x4 pRe[2], pIm[2];
#pragma unroll
                for (int m = 0; m < 2; ++m) {
                    pRe[m] = (f32x4){0.f, 0.f, 0.f, 0.f};
                    pIm[m] = (f32x4){0.f, 0.f, 0.f, 0.f};
                }
#pragma unroll
                for (int ks = 0; ks < 2; ++ks) {
                    int kb = ks * 32 + lq * 8;
                    short8 br[2], bi[2], bin[2];
#pragma unroll
                    for (int ut = 0; ut < 2; ++ut) {
                        int u = u0 + ut * 16 + lrow;
                        br[ut] = *(const short8*)&XTre[u * AP + kb];
                        bi[ut] = *(const short8*)&XTim[u * AP + kb];
                        bin[ut] = bi[ut] ^ (short)0x8000;
                    }
                    int o = ot * 16 + lrow;
                    short8 ar = *(const short8*)&WSre[o * AP + kb];
                    short8 ai = *(const short8*)&WSim[o * AP + kb];
#pragma unroll
                    for (int ut = 0; ut < 2; ++ut) {
                        pRe[ut] = __builtin_amdgcn_mfma_f32_16x16x32_bf16(ai, bin[ut], pRe[ut], 0, 0, 0);
                        pRe[ut] = __builtin_amdgcn_mfma_f32_16x16x32_bf16(ar, br[ut],  pRe[ut], 0, 0, 0);
                        pIm[ut] = __builtin_amdgcn_mfma_f32_16x16x32_bf16(ai, br[ut],  pIm[ut], 0, 0, 0);
                        pIm[ut] = __builtin_amdgcn_mfma_f32_16x16x32_bf16(ar, bi[ut],  pIm[ut], 0, 0, 0);
                    }
                }
#pragma unroll
                for (int ut = 0; ut < 2; ++ut) {
                    int u = u0 + ut * 16 + lrow;
                    float sn, cn;
                    __sincosf(-2.f * PI_F * (float)((u * p) & 127) / 128.f, &sn, &cn);
#pragma unroll
                    for (int e = 0; e < 4; ++e) {
                        fRe[ut][e] += pRe[ut][e] * cn - pIm[ut][e] * sn;
                        fIm[ut][e] += pIm[ut][e] * cn + pRe[ut][e] * sn;
                    }
                }
            }
#pragma unroll
            for (int ut = 0; ut < 2; ++ut) {
                int u = u0 + ut * 16 + lrow;
#pragma unroll
                for (int e = 0; e < 4; ++e) {
                    int o = ot * 16 + lq * 4 + e;
                    size_t idx = ((size_t)(b * 64 + o) * WF + v) * 128 + u;
                    Zre[idx] = f2b(fRe[ut][e]);
                    Zim[idx] = f2b(fIm[ut][e]);
                }
            }
        }
    }

    // ================= manual grid barrier (all 256 blocks co-resident) =================
    __syncthreads();                         // drains vmcnt before barrier (compiler-emitted)
    if (t == 0) {
        __threadfence();                     // release: write back this XCD's L2
        atomicAdd(ctr, 1u);
        while (atomicAdd(ctr, 0u) < 256u) __builtin_amdgcn_s_sleep(8);
    }
    __syncthreads();
    __threadfence();                         // acquire: invalidate caches before reading Z

    // ================= phase B: per-ch S4 + S5 (R15 k_inv verbatim) =================
    {
        ushort* B1 = POOL;                        // [80][B2P] 44.8 KB
        ushort* B2 = POOL + 80 * B2P;             // [128][B3P] 43.0 KB
        int ch = bid;
        for (int c = t; c < 2080; c += 1024) {    // stage Z -> [v][kp*128+u]
            int r = c >> 5, sl = c & 31;
            const ushort* src = (sl < 16 ? Zre : Zim) + ((size_t)ch * WF + r) * 128 + (sl & 15) * 8;
            *(short8*)&B1[r * B2P + sl * 8] = *(const short8*)src;
        }
        if (t < 480) {                            // zero pad rows v=65..79
            int r = 65 + (t >> 5), sl = t & 31;
            short8 z = {0, 0, 0, 0, 0, 0, 0, 0};
            *(short8*)&B1[r * B2P + sl * 8] = z;
        }
        __syncthreads();

        // ---- S4: C[m=(part,h)][n=v]; wave owns m-tile = wave, all 5 n-tiles ----
        {
            int mt = wave;
            f32x4 acc[5];
#pragma unroll
            for (int nt = 0; nt < 5; ++nt) acc[nt] = (f32x4){0.f, 0.f, 0.f, 0.f};
#pragma unroll
            for (int ks = 0; ks < 8; ++ks) {
                short8 a = *(const short8*)&A4[(mt * 16 + lrow) * 256 + ks * 32 + lq * 8];
#pragma unroll
                for (int nt = 0; nt < 5; ++nt) {
                    short8 b = *(short8*)&B1[(nt * 16 + lrow) * B2P + ks * 32 + lq * 8];
                    acc[nt] = __builtin_amdgcn_mfma_f32_16x16x32_bf16(a, b, acc[nt], 0, 0, 0);
                }
            }
            int part = mt >= 8;
            int h0 = mt * 16 + lq * 4 - part * 128;
#pragma unroll
            for (int nt = 0; nt < 5; ++nt) {
                int v = nt * 16 + lrow;
#pragma unroll
                for (int e = 0; e < 4; ++e)
                    B2[(h0 + e) * B3P + part * 80 + v] = f2b(acc[nt][e]);
            }
        }
        __syncthreads();

        // ---- S5 (swapped): C[m=h][n=x]; wave (mt=w&7, nh=w>>3): 4 n-tiles ----
        {
            int mt = wave & 7, nh = wave >> 3;
            f32x4 acc[4];
#pragma unroll
            for (int jn = 0; jn < 4; ++jn) acc[jn] = (f32x4){0.f, 0.f, 0.f, 0.f};
#pragma unroll
            for (int ks = 0; ks < 5; ++ks) {
                short8 a = *(short8*)&B2[(mt * 16 + lrow) * B3P + ks * 32 + lq * 8];
#pragma unroll
                for (int jn = 0; jn < 4; ++jn) {
                    int nt = nh * 4 + jn;
                    short8 b = *(const short8*)&A5[(nt * 16 + lrow) * 160 + ks * 32 + lq * 8];
                    acc[jn] = __builtin_amdgcn_mfma_f32_16x16x32_bf16(a, b, acc[jn], 0, 0, 0);
                }
            }
            float bo = bias[ch & 63];
            float* go = out + (size_t)ch * 16384;
#pragma unroll
            for (int jn = 0; jn < 4; ++jn) {
                int xx = (nh * 4 + jn) * 16 + lrow;
#pragma unroll
                for (int e = 0; e < 4; ++e) {
                    int h = mt * 16 + lq * 4 + e;
                    go[h * 128 + xx] = acc[jn][e] + bo;
                }
            }
        }
    }
}

extern "C" void kernel_launch(void* const* d_in, const int* in_sizes, int n_in,
                              void* d_out, int out_size, void* d_ws, size_t ws_size,
                              hipStream_t stream) {
    const float* x = (const float*)d_in[0];      // [4,64,128,128]
    const float* w = (const float*)d_in[1];      // [64,64,3,3]
    const float* bias = (const float*)d_in[2];   // [64]
    float* out = (float*)d_out;                  // [4,64,128,128]

    char* ws = (char*)d_ws;
    unsigned int* ctr = (unsigned int*)(ws + 0);
    ushort* A4   = (ushort*)(ws + 172032);
    ushort* A5   = (ushort*)(ws + 303104);
    ushort* WvRe = (ushort*)(ws + 344064);
    ushort* WvIm = (ushort*)(ws + 1941504);
    ushort* XsRe = (ushort*)(ws + 12058624);
    ushort* XsIm = (ushort*)(ws + 16318464);
    ushort* Zre  = (ushort*)(ws + 20578304);
    ushort* Zim  = (ushort*)(ws + 24838144);

    k_fwd<<<NB * NC, 1024, 0, stream>>>(x, w, XsRe, XsIm, WvRe, WvIm, A4, A5, ctr);
    k_mi<<<256, 1024, 0, stream>>>(XsRe, XsIm, WvRe, WvIm, Zre, Zim, A4, A5, bias, out, ctr);
}

// Round 17
// 48.618 us; speedup vs baseline: 2.6912x; 2.6912x over previous
//
#include <hip/hip_runtime.h>

#define PI_F 3.14159265358979323846f

// Problem constants: B=4, Cin=Cout=64, H=W=128, Wf=65, K=3
#define HH 128
#define WW 128
#define WF 65
#define NB 4
#define NC 64
#define CPLX_PER_IMG (HH * WF)                  // 8320

typedef __attribute__((ext_vector_type(8))) short short8;
typedef __attribute__((ext_vector_type(4))) float f32x4;

__device__ __forceinline__ ushort f2b(float f) {   // f32 -> bf16 RNE
    unsigned u = __float_as_uint(f);
    u += 0x7fffu + ((u >> 16) & 1u);
    return (ushort)(u >> 16);
}

// ===================== ws layout (bytes) =====================
// A4: [256][256] @ 172032 | A5: [128][160] @ 303104
// WvRe/WvIm @ 344064/1941504 (2x 1597440)
// XsRe/XsIm @ 12058624/16318464 (2x 4259840) | Zre/Zim @ 20578304/24838144

// ---------------- graft item: Wv planes + A4 + A5 (idx in [86016, 970752)) -------------
__device__ __forceinline__ void pre_item_tail(int idx, const float* __restrict__ w,
                                              ushort* __restrict__ A4,
                                              ushort* __restrict__ A5,
                                              ushort* __restrict__ WvRe,
                                              ushort* __restrict__ WvIm) {
    if (idx < 151552) {                      // A4[m][k2]: inv col DFT, /128
        int j = idx - 86016;
        int m = j >> 8, k2 = j & 255;
        int part = m >> 7, h = m & 127;
        int kp = k2 >> 7, u = k2 & 127;
        float s, c;
        __sincosf(2.f * PI_F * (float)((u * h) & 127) / 128.f, &s, &c);
        float val = part == 0 ? (kp == 0 ? c : -s) : (kp == 0 ? s : c);
        A4[j] = f2b(val * (1.f / 128.f));
    } else if (idx < 172032) {               // A5[x][k2]: c2r, /128
        int j = idx - 151552;
        int x = j / 160, k2 = j - x * 160;
        int part = k2 / 80, v = k2 - part * 80;
        float s, c;
        __sincosf(2.f * PI_F * (float)((v * x) & 127) / 128.f, &s, &c);
        float cv = (v == 0 || v == 64) ? 1.f : 2.f;
        float val = (v < 65) ? (part == 0 ? cv * c : -cv * s) * (1.f / 128.f) : 0.f;
        A5[j] = f2b(val);
    } else {                                 // Wv[p][v][o][i]
        int xw = idx - 172032;               // 0..798719
        int i = xw & 63;
        int o = (xw >> 6) & 63;
        int pv = xw >> 12;
        int p = pv / WF;
        int v = pv % WF;
        const float* wp = w + ((size_t)o * 64 + i) * 9 + p * 3;
        float re = wp[0], im = 0.f;
#pragma unroll
        for (int q = 1; q <= 2; ++q) {
            int k = (v * q) & 127;
            float s, c;
            __sincosf(-2.f * PI_F * (float)k / 128.f, &s, &c);
            re += wp[q] * c;
            im += wp[q] * s;
        }
        WvRe[xw] = f2b(re);
        WvIm[xw] = f2b(im);
    }
}

// ---------------- k_fwd: R15 + register prefetch of S1 x-frags ----------
#define B2P 280
#define A1P 136
__global__ __launch_bounds__(1024) void k_fwd(const float* __restrict__ x,
                                              const float* __restrict__ w,
                                              ushort* __restrict__ XsRe,
                                              ushort* __restrict__ XsIm,
                                              ushort* __restrict__ WvRe,
                                              ushort* __restrict__ WvIm,
                                              ushort* __restrict__ A4,
                                              ushort* __restrict__ A5) {
    __shared__ ushort A1L[160 * A1P];        // 42.5 KB
    __shared__ ushort B2[80 * B2P];          // 44.8 KB
    __shared__ __align__(16) float2 TW[128]; // e^{+2pi i k/128}
    int t = threadIdx.x;
    int img = blockIdx.x;
    const float* gx = x + (size_t)img * 16384;
    int lane = t & 63, wave = t >> 6;        // wave 0..15
    int lrow = lane & 15, lq = lane >> 4;

    // ---- prefetch S1 B-frags (global x, independent of LDS) ----
    int g = wave >> 3, nt8 = wave & 7;
    int hrow = nt8 * 16 + lrow;
    short8 bfr[4];
#pragma unroll
    for (int ks = 0; ks < 4; ++ks) {
        const float* xp = gx + hrow * 128 + ks * 32 + lq * 8;
        float4 f0 = *(const float4*)xp;
        float4 f1 = *(const float4*)(xp + 4);
        bfr[ks][0] = (short)f2b(f0.x); bfr[ks][1] = (short)f2b(f0.y);
        bfr[ks][2] = (short)f2b(f0.z); bfr[ks][3] = (short)f2b(f0.w);
        bfr[ks][4] = (short)f2b(f1.x); bfr[ks][5] = (short)f2b(f1.y);
        bfr[ks][6] = (short)f2b(f1.z); bfr[ks][7] = (short)f2b(f1.w);
    }

    // ---- phase 0: A1L gen || TW gen || graft (x loads in flight above) ----
    if (t < 128) {
        float s, c;
        __sincosf(2.f * PI_F * (float)t / 128.f, &s, &c);
        TW[t] = make_float2(c, s);
    }
    for (int idx = t; idx < 20480; idx += 1024) {
        int m = idx >> 7, k = idx & 127;
        int part = m / 80, v = m - part * 80;
        float s, c;
        __sincosf(2.f * PI_F * (float)((v * k) & 127) / 128.f, &s, &c);
        float val = (v < 65) ? (part ? -s : c) : 0.f;
        A1L[m * A1P + k] = f2b(val);
    }
    {
        int gtid = img * 1024 + t;           // [0, 262144)
        for (int idx = 86016 + gtid; idx < 970752; idx += 262144)
            pre_item_tail(idx, w, A4, A5, WvRe, WvIm);
    }
    __syncthreads();

    // ---- S1: C[m=(part,v)][n=h]; B-frags already in registers ----
    {
        f32x4 acc[5];
#pragma unroll
        for (int j = 0; j < 5; ++j) acc[j] = (f32x4){0.f, 0.f, 0.f, 0.f};
#pragma unroll
        for (int ks = 0; ks < 4; ++ks) {
#pragma unroll
            for (int j = 0; j < 5; ++j) {
                int mt = g * 5 + j;
                short8 a = *(const short8*)&A1L[(mt * 16 + lrow) * A1P + ks * 32 + lq * 8];
                acc[j] = __builtin_amdgcn_mfma_f32_16x16x32_bf16(a, bfr[ks], acc[j], 0, 0, 0);
            }
        }
#pragma unroll
        for (int j = 0; j < 5; ++j) {
            int m0 = (g * 5 + j) * 16 + lq * 4;
            int part = m0 >= 80;
            int v0 = m0 - part * 80;
#pragma unroll
            for (int e = 0; e < 4; ++e)
                B2[(v0 + e) * B2P + part * 128 + hrow] = f2b(acc[j][e]);
        }
    }
    __syncthreads();

    // ---- S2 (swapped): C[m=v][n=(part,u)]; B-frags from TW ----
    {
        int nt = wave;
        int part = nt >= 8;
        int um = (nt & 7) * 16 + lrow;
        f32x4 acc[5];
#pragma unroll
        for (int mt = 0; mt < 5; ++mt) acc[mt] = (f32x4){0.f, 0.f, 0.f, 0.f};
#pragma unroll
        for (int ks = 0; ks < 8; ++ks) {
            int kp = ks >> 2;
            int hbase = (ks & 3) * 32 + lq * 8;
            short8 bb;
            int idx = (um * hbase) & 127;
#pragma unroll
            for (int e = 0; e < 8; ++e) {
                float2 tw = TW[idx];
                float val = !part ? (kp == 0 ? tw.x : tw.y)
                                  : (kp == 0 ? -tw.y : tw.x);
                bb[e] = (short)f2b(val);
                idx = (idx + um) & 127;
            }
#pragma unroll
            for (int mt = 0; mt < 5; ++mt) {
                short8 a = *(short8*)&B2[(mt * 16 + lrow) * B2P + ks * 32 + lq * 8];
                acc[mt] = __builtin_amdgcn_mfma_f32_16x16x32_bf16(a, bb, acc[mt], 0, 0, 0);
            }
        }
        int u = (nt & 7) * 16 + lrow;
        int u_out = (u + 64) & 127;
        int du = u_out - 64;
        ushort* dimg = (part ? XsIm : XsRe) + (size_t)img * CPLX_PER_IMG;
#pragma unroll
        for (int mt = 0; mt < 5; ++mt)
#pragma unroll
            for (int e = 0; e < 4; ++e) {
                int v_in = mt * 16 + lq * 4 + e;
                if (v_in < 65) {
                    int v_out = v_in + 32; if (v_out >= 65) v_out -= 65;
                    int dv = v_out - 64;
                    bool keep = (du * du + dv * dv) > 900;
                    dimg[v_out * 128 + u_out] = keep ? f2b(acc[mt][e]) : (ushort)0;
                }
            }
    }
}

// ---------------- k_gemm: single-stage (XT + all 3 Wv planes), one barrier ----------
// grid = 260, 256 threads. LDS: XT 36.9 KB + WS[3] 55.3 KB = 92.2 KB -> 1 block/CU.
#define AP 72
__global__ __launch_bounds__(256) void k_gemm(const ushort* __restrict__ XsRe,
                                              const ushort* __restrict__ XsIm,
                                              const ushort* __restrict__ WvRe,
                                              const ushort* __restrict__ WvIm,
                                              ushort* __restrict__ Zre,
                                              ushort* __restrict__ Zim) {
    __shared__ ushort XTre[128 * AP], XTim[128 * AP];     // [u][i]
    __shared__ ushort WSre[3 * 64 * AP], WSim[3 * 64 * AP];  // [p][o][i]
    int t = threadIdx.x;
    int v = blockIdx.x >> 2;
    int b = blockIdx.x & 3;
    {   // ---- stage X transposed [u][i], both planes ----
        int u = t & 127, qh = t >> 7;
#pragma unroll
        for (int q8 = 0; q8 < 8; ++q8) {
            int q = qh * 8 + q8;
            ushort re4[4], im4[4];
#pragma unroll
            for (int c = 0; c < 4; ++c) {
                int i = q * 4 + c;
                size_t off = ((size_t)(b * 64 + i) * WF + v) * 128 + u;
                re4[c] = XsRe[off];
                im4[c] = XsIm[off];
            }
            *(ushort4*)&XTre[u * AP + q * 4] = make_ushort4(re4[0], re4[1], re4[2], re4[3]);
            *(ushort4*)&XTim[u * AP + q * 4] = make_ushort4(im4[0], im4[1], im4[2], im4[3]);
        }
    }
    {   // ---- stage all 3 Wv p-planes ----
#pragma unroll
        for (int pp = 0; pp < 3; ++pp) {
            const ushort* gr = WvRe + ((size_t)(pp * WF + v)) * 4096;
            const ushort* gi = WvIm + ((size_t)(pp * WF + v)) * 4096;
#pragma unroll
            for (int cc = 0; cc < 2; ++cc) {
                int c = t + cc * 256;        // 512 chunks of 8 elems
                int o = c >> 3, i0 = (c & 7) * 8;
                *(short8*)&WSre[pp * 64 * AP + o * AP + i0] = *(const short8*)&gr[c * 8];
                *(short8*)&WSim[pp * 64 * AP + o * AP + i0] = *(const short8*)&gi[c * 8];
            }
        }
    }
    __syncthreads();                         // ONE barrier; compute is barrier-free below

    int lane = t & 63, wave = t >> 6;
    int lrow = lane & 15, lq = lane >> 4;
    int u0 = wave * 32;
    f32x4 fRe[8], fIm[8];
#pragma unroll
    for (int m = 0; m < 8; ++m) {
        fRe[m] = (f32x4){0.f, 0.f, 0.f, 0.f};
        fIm[m] = (f32x4){0.f, 0.f, 0.f, 0.f};
    }
    for (int p = 0; p < 3; ++p) {
        const ushort* wsr = WSre + p * 64 * AP;
        const ushort* wsi = WSim + p * 64 * AP;
        f32x4 pRe[8], pIm[8];
#pragma unroll
        for (int m = 0; m < 8; ++m) {
            pRe[m] = (f32x4){0.f, 0.f, 0.f, 0.f};
            pIm[m] = (f32x4){0.f, 0.f, 0.f, 0.f};
        }
#pragma unroll
        for (int ks = 0; ks < 2; ++ks) {
            int kb = ks * 32 + lq * 8;
            short8 br[2], bi[2], bin[2];
#pragma unroll
            for (int ut = 0; ut < 2; ++ut) {
                int u = u0 + ut * 16 + lrow;
                br[ut] = *(const short8*)&XTre[u * AP + kb];
                bi[ut] = *(const short8*)&XTim[u * AP + kb];
                bin[ut] = bi[ut] ^ (short)0x8000;
            }
#pragma unroll
            for (int ot = 0; ot < 4; ++ot) {
                int o = ot * 16 + lrow;
                short8 ar = *(const short8*)&wsr[o * AP + kb];
                short8 ai = *(const short8*)&wsi[o * AP + kb];
#pragma unroll
                for (int ut = 0; ut < 2; ++ut) {
                    int m = ot * 2 + ut;
                    pRe[m] = __builtin_amdgcn_mfma_f32_16x16x32_bf16(ai, bin[ut], pRe[m], 0, 0, 0);
                    pRe[m] = __builtin_amdgcn_mfma_f32_16x16x32_bf16(ar, br[ut],  pRe[m], 0, 0, 0);
                    pIm[m] = __builtin_amdgcn_mfma_f32_16x16x32_bf16(ai, br[ut],  pIm[m], 0, 0, 0);
                    pIm[m] = __builtin_amdgcn_mfma_f32_16x16x32_bf16(ar, bi[ut],  pIm[m], 0, 0, 0);
                }
            }
        }
#pragma unroll
        for (int ut = 0; ut < 2; ++ut) {
            int u = u0 + ut * 16 + lrow;
            float sn, cn;
            __sincosf(-2.f * PI_F * (float)(u * p) / 128.f, &sn, &cn);
#pragma unroll
            for (int ot = 0; ot < 4; ++ot) {
                int m = ot * 2 + ut;
#pragma unroll
                for (int e = 0; e < 4; ++e) {
                    fRe[m][e] += pRe[m][e] * cn - pIm[m][e] * sn;
                    fIm[m][e] += pIm[m][e] * cn + pRe[m][e] * sn;
                }
            }
        }
    }
#pragma unroll
    for (int ot = 0; ot < 4; ++ot)
#pragma unroll
        for (int ut = 0; ut < 2; ++ut) {
            int m = ot * 2 + ut;
            int u = u0 + ut * 16 + lrow;
#pragma unroll
            for (int e = 0; e < 4; ++e) {
                int o = ot * 16 + lq * 4 + e;
                size_t idx = ((size_t)(b * 64 + o) * WF + v) * 128 + u;
                Zre[idx] = f2b(fRe[m][e]);
                Zim[idx] = f2b(fIm[m][e]);
            }
        }
}

// ---------------- k_inv: per-ch S4 + S5 (R15 exact) ----------------
#define B3P 168
__global__ __launch_bounds__(1024) void k_inv(const ushort* __restrict__ Zre,
                                              const ushort* __restrict__ Zim,
                                              const ushort* __restrict__ A4,
                                              const ushort* __restrict__ A5,
                                              const float* __restrict__ bias,
                                              float* __restrict__ out) {
    __shared__ ushort B1[80 * B2P];          // 44.8 KB
    __shared__ ushort B2[128 * B3P];         // 43.0 KB
    int t = threadIdx.x;
    int ch = blockIdx.x;
    for (int c = t; c < 2080; c += 1024) {   // stage Z -> [v][kp*128+u]
        int r = c >> 5, sl = c & 31;
        const ushort* src = (sl < 16 ? Zre : Zim) + ((size_t)ch * WF + r) * 128 + (sl & 15) * 8;
        *(short8*)&B1[r * B2P + sl * 8] = *(const short8*)src;
    }
    if (t < 480) {                           // zero pad rows v=65..79
        int r = 65 + (t >> 5), sl = t & 31;
        short8 z = {0, 0, 0, 0, 0, 0, 0, 0};
        *(short8*)&B1[r * B2P + sl * 8] = z;
    }
    __syncthreads();
    int lane = t & 63, wave = t >> 6;        // wave 0..15
    int lrow = lane & 15, lq = lane >> 4;

    // ---- S4: C[m=(part,h)][n=v]; wave owns m-tile = wave, all 5 n-tiles ----
    {
        int mt = wave;
        f32x4 acc[5];
#pragma unroll
        for (int nt = 0; nt < 5; ++nt) acc[nt] = (f32x4){0.f, 0.f, 0.f, 0.f};
#pragma unroll
        for (int ks = 0; ks < 8; ++ks) {
            short8 a = *(const short8*)&A4[(mt * 16 + lrow) * 256 + ks * 32 + lq * 8];
#pragma unroll
            for (int nt = 0; nt < 5; ++nt) {
                short8 b = *(short8*)&B1[(nt * 16 + lrow) * B2P + ks * 32 + lq * 8];
                acc[nt] = __builtin_amdgcn_mfma_f32_16x16x32_bf16(a, b, acc[nt], 0, 0, 0);
            }
        }
        int part = mt >= 8;
        int h0 = mt * 16 + lq * 4 - part * 128;
#pragma unroll
        for (int nt = 0; nt < 5; ++nt) {
            int v = nt * 16 + lrow;
#pragma unroll
            for (int e = 0; e < 4; ++e)
                B2[(h0 + e) * B3P + part * 80 + v] = f2b(acc[nt][e]);
        }
    }
    __syncthreads();

    // ---- S5 (swapped): C[m=h][n=x]; wave (mt=w&7, nh=w>>3): 4 n-tiles ----
    {
        int mt = wave & 7, nh = wave >> 3;
        f32x4 acc[4];
#pragma unroll
        for (int jn = 0; jn < 4; ++jn) acc[jn] = (f32x4){0.f, 0.f, 0.f, 0.f};
#pragma unroll
        for (int ks = 0; ks < 5; ++ks) {
            short8 a = *(short8*)&B2[(mt * 16 + lrow) * B3P + ks * 32 + lq * 8];
#pragma unroll
            for (int jn = 0; jn < 4; ++jn) {
                int nt = nh * 4 + jn;
                short8 b = *(const short8*)&A5[(nt * 16 + lrow) * 160 + ks * 32 + lq * 8];
                acc[jn] = __builtin_amdgcn_mfma_f32_16x16x32_bf16(a, b, acc[jn], 0, 0, 0);
            }
        }
        float bo = bias[ch & 63];
        float* go = out + (size_t)ch * 16384;
#pragma unroll
        for (int jn = 0; jn < 4; ++jn) {
            int xx = (nh * 4 + jn) * 16 + lrow;
#pragma unroll
            for (int e = 0; e < 4; ++e) {
                int h = mt * 16 + lq * 4 + e;
                go[h * 128 + xx] = acc[jn][e] + bo;
            }
        }
    }
}

extern "C" void kernel_launch(void* const* d_in, const int* in_sizes, int n_in,
                              void* d_out, int out_size, void* d_ws, size_t ws_size,
                              hipStream_t stream) {
    const float* x = (const float*)d_in[0];      // [4,64,128,128]
    const float* w = (const float*)d_in[1];      // [64,64,3,3]
    const float* bias = (const float*)d_in[2];   // [64]
    float* out = (float*)d_out;                  // [4,64,128,128]

    char* ws = (char*)d_ws;
    ushort* A4   = (ushort*)(ws + 172032);
    ushort* A5   = (ushort*)(ws + 303104);
    ushort* WvRe = (ushort*)(ws + 344064);
    ushort* WvIm = (ushort*)(ws + 1941504);
    ushort* XsRe = (ushort*)(ws + 12058624);
    ushort* XsIm = (ushort*)(ws + 16318464);
    ushort* Zre  = (ushort*)(ws + 20578304);
    ushort* Zim  = (ushort*)(ws + 24838144);

    k_fwd<<<NB * NC, 1024, 0, stream>>>(x, w, XsRe, XsIm, WvRe, WvIm, A4, A5);
    k_gemm<<<WF * NB, 256, 0, stream>>>(XsRe, XsIm, WvRe, WvIm, Zre, Zim);
    k_inv<<<NB * NC, 1024, 0, stream>>>(Zre, Zim, A4, A5, bias, out);
}

// Round 18
// 46.889 us; speedup vs baseline: 2.7905x; 1.0369x over previous
//
#include <hip/hip_runtime.h>

#define PI_F 3.14159265358979323846f

// Problem constants: B=4, Cin=Cout=64, H=W=128, Wf=65, K=3
#define HH 128
#define WW 128
#define WF 65
#define NB 4
#define NC 64
#define CPLX_PER_IMG (HH * WF)                  // 8320

typedef __attribute__((ext_vector_type(8))) short short8;
typedef __attribute__((ext_vector_type(4))) float f32x4;

__device__ __forceinline__ ushort f2b(float f) {   // f32 -> bf16 RNE
    unsigned u = __float_as_uint(f);
    u += 0x7fffu + ((u >> 16) & 1u);
    return (ushort)(u >> 16);
}

// ===================== ws layout (bytes) =====================
// A4: [256][256] @ 172032 | A5: [128][160] @ 303104
// WvRe/WvIm @ 344064/1941504 (2x 1597440)
// XsRe/XsIm @ 12058624/16318464 (2x 4259840) | Zre/Zim @ 20578304/24838144

// ---------------- graft item: Wv planes + A4 + A5 (idx in [86016, 970752)) -------------
__device__ __forceinline__ void pre_item_tail(int idx, const float* __restrict__ w,
                                              ushort* __restrict__ A4,
                                              ushort* __restrict__ A5,
                                              ushort* __restrict__ WvRe,
                                              ushort* __restrict__ WvIm) {
    if (idx < 151552) {                      // A4[m][k2]: inv col DFT, /128
        int j = idx - 86016;
        int m = j >> 8, k2 = j & 255;
        int part = m >> 7, h = m & 127;
        int kp = k2 >> 7, u = k2 & 127;
        float s, c;
        __sincosf(2.f * PI_F * (float)((u * h) & 127) / 128.f, &s, &c);
        float val = part == 0 ? (kp == 0 ? c : -s) : (kp == 0 ? s : c);
        A4[j] = f2b(val * (1.f / 128.f));
    } else if (idx < 172032) {               // A5[x][k2]: c2r, /128
        int j = idx - 151552;
        int x = j / 160, k2 = j - x * 160;
        int part = k2 / 80, v = k2 - part * 80;
        float s, c;
        __sincosf(2.f * PI_F * (float)((v * x) & 127) / 128.f, &s, &c);
        float cv = (v == 0 || v == 64) ? 1.f : 2.f;
        float val = (v < 65) ? (part == 0 ? cv * c : -cv * s) * (1.f / 128.f) : 0.f;
        A5[j] = f2b(val);
    } else {                                 // Wv[p][v][o][i]
        int xw = idx - 172032;               // 0..798719
        int i = xw & 63;
        int o = (xw >> 6) & 63;
        int pv = xw >> 12;
        int p = pv / WF;
        int v = pv % WF;
        const float* wp = w + ((size_t)o * 64 + i) * 9 + p * 3;
        float re = wp[0], im = 0.f;
#pragma unroll
        for (int q = 1; q <= 2; ++q) {
            int k = (v * q) & 127;
            float s, c;
            __sincosf(-2.f * PI_F * (float)k / 128.f, &s, &c);
            re += wp[q] * c;
            im += wp[q] * s;
        }
        WvRe[xw] = f2b(re);
        WvIm[xw] = f2b(im);
    }
}

// ---------------- k_fwd: self-sufficient; no x-staging; S2 via twiddle table ----------
// grid 256, 1024 threads (16 waves). LDS: A1L[160][136] 42.5 KB + B2[80][280] 44.8 KB
// + TW[128] 1 KB = 88.3 KiB.
#define B2P 280
#define A1P 136
__global__ __launch_bounds__(1024) void k_fwd(const float* __restrict__ x,
                                              const float* __restrict__ w,
                                              ushort* __restrict__ XsRe,
                                              ushort* __restrict__ XsIm,
                                              ushort* __restrict__ WvRe,
                                              ushort* __restrict__ WvIm,
                                              ushort* __restrict__ A4,
                                              ushort* __restrict__ A5) {
    __shared__ ushort A1L[160 * A1P];        // 42.5 KB
    __shared__ ushort B2[80 * B2P];          // 44.8 KB
    __shared__ __align__(16) float2 TW[128]; // e^{+2pi i k/128}
    int t = threadIdx.x;
    int img = blockIdx.x;
    const float* gx = x + (size_t)img * 16384;

    // ---- phase 0: A1L gen || TW gen || graft (no x staging) ----
    if (t < 128) {
        float s, c;
        __sincosf(2.f * PI_F * (float)t / 128.f, &s, &c);
        TW[t] = make_float2(c, s);
    }
    for (int idx = t; idx < 20480; idx += 1024) {
        int m = idx >> 7, k = idx & 127;
        int part = m / 80, v = m - part * 80;
        float s, c;
        __sincosf(2.f * PI_F * (float)((v * k) & 127) / 128.f, &s, &c);
        float val = (v < 65) ? (part ? -s : c) : 0.f;
        A1L[m * A1P + k] = f2b(val);
    }
    {
        int gtid = img * 1024 + t;           // [0, 262144)
        for (int idx = 86016 + gtid; idx < 970752; idx += 262144)
            pre_item_tail(idx, w, A4, A5, WvRe, WvIm);
    }
    __syncthreads();

    int lane = t & 63, wave = t >> 6;        // wave 0..15
    int lrow = lane & 15, lq = lane >> 4;

    // ---- S1: C[m=(part,v)][n=h]; wave (g=w>>3, nt=w&7); B-frag direct from global x ----
    {
        int g = wave >> 3, nt = wave & 7;
        int hrow = nt * 16 + lrow;
        f32x4 acc[5];
#pragma unroll
        for (int j = 0; j < 5; ++j) acc[j] = (f32x4){0.f, 0.f, 0.f, 0.f};
#pragma unroll
        for (int ks = 0; ks < 4; ++ks) {
            const float* xp = gx + hrow * 128 + ks * 32 + lq * 8;
            float4 f0 = *(const float4*)xp;
            float4 f1 = *(const float4*)(xp + 4);
            short8 b;
            b[0] = (short)f2b(f0.x); b[1] = (short)f2b(f0.y);
            b[2] = (short)f2b(f0.z); b[3] = (short)f2b(f0.w);
            b[4] = (short)f2b(f1.x); b[5] = (short)f2b(f1.y);
            b[6] = (short)f2b(f1.z); b[7] = (short)f2b(f1.w);
#pragma unroll
            for (int j = 0; j < 5; ++j) {
                int mt = g * 5 + j;
                short8 a = *(const short8*)&A1L[(mt * 16 + lrow) * A1P + ks * 32 + lq * 8];
                acc[j] = __builtin_amdgcn_mfma_f32_16x16x32_bf16(a, b, acc[j], 0, 0, 0);
            }
        }
#pragma unroll
        for (int j = 0; j < 5; ++j) {
            int m0 = (g * 5 + j) * 16 + lq * 4;
            int part = m0 >= 80;
            int v0 = m0 - part * 80;
#pragma unroll
            for (int e = 0; e < 4; ++e)
                B2[(v0 + e) * B2P + part * 128 + hrow] = f2b(acc[j][e]);
        }
    }
    __syncthreads();

    // ---- S2 (swapped): C[m=v][n=(part,u)]; wave owns n-tile = wave; B-frags from TW ----
    {
        int nt = wave;
        int part = nt >= 8;
        int um = (nt & 7) * 16 + lrow;       // u_m of the A2 row this lane supplies
        f32x4 acc[5];
#pragma unroll
        for (int mt = 0; mt < 5; ++mt) acc[mt] = (f32x4){0.f, 0.f, 0.f, 0.f};
#pragma unroll
        for (int ks = 0; ks < 8; ++ks) {
            int kp = ks >> 2;
            int hbase = (ks & 3) * 32 + lq * 8;
            short8 bfr;
            int idx = (um * hbase) & 127;
#pragma unroll
            for (int e = 0; e < 8; ++e) {
                float2 tw = TW[idx];
                // A2 value: part0: (kp==0? c : s); part1: (kp==0? -s : c)
                float val = !part ? (kp == 0 ? tw.x : tw.y)
                                  : (kp == 0 ? -tw.y : tw.x);
                bfr[e] = (short)f2b(val);
                idx = (idx + um) & 127;
            }
#pragma unroll
            for (int mt = 0; mt < 5; ++mt) {
                short8 a = *(short8*)&B2[(mt * 16 + lrow) * B2P + ks * 32 + lq * 8];
                acc[mt] = __builtin_amdgcn_mfma_f32_16x16x32_bf16(a, bfr, acc[mt], 0, 0, 0);
            }
        }
        int u = (nt & 7) * 16 + lrow;
        int u_out = (u + 64) & 127;
        int du = u_out - 64;
        ushort* dimg = (part ? XsIm : XsRe) + (size_t)img * CPLX_PER_IMG;
#pragma unroll
        for (int mt = 0; mt < 5; ++mt)
#pragma unroll
            for (int e = 0; e < 4; ++e) {
                int v_in = mt * 16 + lq * 4 + e;
                if (v_in < 65) {
                    int v_out = v_in + 32; if (v_out >= 65) v_out -= 65;
                    int dv = v_out - 64;
                    bool keep = (du * du + dv * dv) > 900;
                    dimg[v_out * 128 + u_out] = keep ? f2b(acc[mt][e]) : (ushort)0;
                }
            }
    }
}

// ---------------- k_gemm: per-(v,b) complex GEMM via bf16 MFMA + phase fold ----------
#define AP 72
__global__ __launch_bounds__(256, 2) void k_gemm(const ushort* __restrict__ XsRe,
                                                 const ushort* __restrict__ XsIm,
                                                 const ushort* __restrict__ WvRe,
                                                 const ushort* __restrict__ WvIm,
                                                 ushort* __restrict__ Zre,
                                                 ushort* __restrict__ Zim) {
    __shared__ ushort XTre[128 * AP], XTim[128 * AP];
    __shared__ ushort WSre[64 * AP],  WSim[64 * AP];
    int t = threadIdx.x;
    int v = blockIdx.x >> 2;
    int b = blockIdx.x & 3;
    {
        int u = t & 127, qh = t >> 7;
#pragma unroll
        for (int q8 = 0; q8 < 8; ++q8) {
            int q = qh * 8 + q8;
            ushort re4[4], im4[4];
#pragma unroll
            for (int c = 0; c < 4; ++c) {
                int i = q * 4 + c;
                size_t off = ((size_t)(b * 64 + i) * WF + v) * 128 + u;
                re4[c] = XsRe[off];
                im4[c] = XsIm[off];
            }
            *(ushort4*)&XTre[u * AP + q * 4] = make_ushort4(re4[0], re4[1], re4[2], re4[3]);
            *(ushort4*)&XTim[u * AP + q * 4] = make_ushort4(im4[0], im4[1], im4[2], im4[3]);
        }
    }
    int lane = t & 63, wave = t >> 6;
    int lrow = lane & 15, lq = lane >> 4;
    int u0 = wave * 32;
    f32x4 fRe[8], fIm[8];
#pragma unroll
    for (int m = 0; m < 8; ++m) {
        fRe[m] = (f32x4){0.f, 0.f, 0.f, 0.f};
        fIm[m] = (f32x4){0.f, 0.f, 0.f, 0.f};
    }
    for (int p = 0; p < 3; ++p) {
        if (p) __syncthreads();
        {
            const ushort* gr = WvRe + ((size_t)(p * WF + v)) * 4096;
            const ushort* gi = WvIm + ((size_t)(p * WF + v)) * 4096;
#pragma unroll
            for (int cc = 0; cc < 2; ++cc) {
                int c = t + cc * 256;
                int o = c >> 3, i0 = (c & 7) * 8;
                *(short8*)&WSre[o * AP + i0] = *(const short8*)&gr[c * 8];
                *(short8*)&WSim[o * AP + i0] = *(const short8*)&gi[c * 8];
            }
        }
        __syncthreads();
        f32x4 pRe[8], pIm[8];
#pragma unroll
        for (int m = 0; m < 8; ++m) {
            pRe[m] = (f32x4){0.f, 0.f, 0.f, 0.f};
            pIm[m] = (f32x4){0.f, 0.f, 0.f, 0.f};
        }
#pragma unroll
        for (int ks = 0; ks < 2; ++ks) {
            int kb = ks * 32 + lq * 8;
            short8 br[2], bi[2], bin[2];
#pragma unroll
            for (int ut = 0; ut < 2; ++ut) {
                int u = u0 + ut * 16 + lrow;
                br[ut] = *(const short8*)&XTre[u * AP + kb];
                bi[ut] = *(const short8*)&XTim[u * AP + kb];
                bin[ut] = bi[ut] ^ (short)0x8000;
            }
#pragma unroll
            for (int ot = 0; ot < 4; ++ot) {
                int o = ot * 16 + lrow;
                short8 ar = *(const short8*)&WSre[o * AP + kb];
                short8 ai = *(const short8*)&WSim[o * AP + kb];
#pragma unroll
                for (int ut = 0; ut < 2; ++ut) {
                    int m = ot * 2 + ut;
                    pRe[m] = __builtin_amdgcn_mfma_f32_16x16x32_bf16(ai, bin[ut], pRe[m], 0, 0, 0);
                    pRe[m] = __builtin_amdgcn_mfma_f32_16x16x32_bf16(ar, br[ut],  pRe[m], 0, 0, 0);
                    pIm[m] = __builtin_amdgcn_mfma_f32_16x16x32_bf16(ai, br[ut],  pIm[m], 0, 0, 0);
                    pIm[m] = __builtin_amdgcn_mfma_f32_16x16x32_bf16(ar, bi[ut],  pIm[m], 0, 0, 0);
                }
            }
        }
#pragma unroll
        for (int ut = 0; ut < 2; ++ut) {
            int u = u0 + ut * 16 + lrow;
            float sn, cn;
            __sincosf(-2.f * PI_F * (float)(u * p) / 128.f, &sn, &cn);
#pragma unroll
            for (int ot = 0; ot < 4; ++ot) {
                int m = ot * 2 + ut;
#pragma unroll
                for (int e = 0; e < 4; ++e) {
                    fRe[m][e] += pRe[m][e] * cn - pIm[m][e] * sn;
                    fIm[m][e] += pIm[m][e] * cn + pRe[m][e] * sn;
                }
            }
        }
    }
#pragma unroll
    for (int ot = 0; ot < 4; ++ot)
#pragma unroll
        for (int ut = 0; ut < 2; ++ut) {
            int m = ot * 2 + ut;
            int u = u0 + ut * 16 + lrow;
#pragma unroll
            for (int e = 0; e < 4; ++e) {
                int o = ot * 16 + lq * 4 + e;
                size_t idx = ((size_t)(b * 64 + o) * WF + v) * 128 + u;
                Zre[idx] = f2b(fRe[m][e]);
                Zim[idx] = f2b(fIm[m][e]);
            }
        }
}

// ---------------- k_inv: per-ch S4 + S5 ----------------
#define B3P 168
__global__ __launch_bounds__(1024) void k_inv(const ushort* __restrict__ Zre,
                                              const ushort* __restrict__ Zim,
                                              const ushort* __restrict__ A4,
                                              const ushort* __restrict__ A5,
                                              const float* __restrict__ bias,
                                              float* __restrict__ out) {
    __shared__ ushort B1[80 * B2P];          // 44.8 KB
    __shared__ ushort B2[128 * B3P];         // 43.0 KB
    int t = threadIdx.x;
    int ch = blockIdx.x;
    for (int c = t; c < 2080; c += 1024) {   // stage Z -> [v][kp*128+u]
        int r = c >> 5, sl = c & 31;
        const ushort* src = (sl < 16 ? Zre : Zim) + ((size_t)ch * WF + r) * 128 + (sl & 15) * 8;
        *(short8*)&B1[r * B2P + sl * 8] = *(const short8*)src;
    }
    if (t < 480) {                           // zero pad rows v=65..79
        int r = 65 + (t >> 5), sl = t & 31;
        short8 z = {0, 0, 0, 0, 0, 0, 0, 0};
        *(short8*)&B1[r * B2P + sl * 8] = z;
    }
    __syncthreads();
    int lane = t & 63, wave = t >> 6;        // wave 0..15
    int lrow = lane & 15, lq = lane >> 4;

    // ---- S4: C[m=(part,h)][n=v]; wave owns m-tile = wave, all 5 n-tiles ----
    {
        int mt = wave;
        f32x4 acc[5];
#pragma unroll
        for (int nt = 0; nt < 5; ++nt) acc[nt] = (f32x4){0.f, 0.f, 0.f, 0.f};
#pragma unroll
        for (int ks = 0; ks < 8; ++ks) {
            short8 a = *(const short8*)&A4[(mt * 16 + lrow) * 256 + ks * 32 + lq * 8];
#pragma unroll
            for (int nt = 0; nt < 5; ++nt) {
                short8 b = *(short8*)&B1[(nt * 16 + lrow) * B2P + ks * 32 + lq * 8];
                acc[nt] = __builtin_amdgcn_mfma_f32_16x16x32_bf16(a, b, acc[nt], 0, 0, 0);
            }
        }
        int part = mt >= 8;
        int h0 = mt * 16 + lq * 4 - part * 128;
#pragma unroll
        for (int nt = 0; nt < 5; ++nt) {
            int v = nt * 16 + lrow;
#pragma unroll
            for (int e = 0; e < 4; ++e)
                B2[(h0 + e) * B3P + part * 80 + v] = f2b(acc[nt][e]);
        }
    }
    __syncthreads();

    // ---- S5 (swapped): C[m=h][n=x]; wave (mt=w&7, nh=w>>3): 4 n-tiles ----
    {
        int mt = wave & 7, nh = wave >> 3;
        f32x4 acc[4];
#pragma unroll
        for (int jn = 0; jn < 4; ++jn) acc[jn] = (f32x4){0.f, 0.f, 0.f, 0.f};
#pragma unroll
        for (int ks = 0; ks < 5; ++ks) {
            short8 a = *(short8*)&B2[(mt * 16 + lrow) * B3P + ks * 32 + lq * 8];
#pragma unroll
            for (int jn = 0; jn < 4; ++jn) {
                int nt = nh * 4 + jn;
                short8 b = *(const short8*)&A5[(nt * 16 + lrow) * 160 + ks * 32 + lq * 8];
                acc[jn] = __builtin_amdgcn_mfma_f32_16x16x32_bf16(a, b, acc[jn], 0, 0, 0);
            }
        }
        float bo = bias[ch & 63];
        float* go = out + (size_t)ch * 16384;
#pragma unroll
        for (int jn = 0; jn < 4; ++jn) {
            int xx = (nh * 4 + jn) * 16 + lrow;
#pragma unroll
            for (int e = 0; e < 4; ++e) {
                int h = mt * 16 + lq * 4 + e;
                go[h * 128 + xx] = acc[jn][e] + bo;
            }
        }
    }
}

extern "C" void kernel_launch(void* const* d_in, const int* in_sizes, int n_in,
                              void* d_out, int out_size, void* d_ws, size_t ws_size,
                              hipStream_t stream) {
    const float* x = (const float*)d_in[0];      // [4,64,128,128]
    const float* w = (const float*)d_in[1];      // [64,64,3,3]
    const float* bias = (const float*)d_in[2];   // [64]
    float* out = (float*)d_out;                  // [4,64,128,128]

    char* ws = (char*)d_ws;
    ushort* A4   = (ushort*)(ws + 172032);
    ushort* A5   = (ushort*)(ws + 303104);
    ushort* WvRe = (ushort*)(ws + 344064);
    ushort* WvIm = (ushort*)(ws + 1941504);
    ushort* XsRe = (ushort*)(ws + 12058624);
    ushort* XsIm = (ushort*)(ws + 16318464);
    ushort* Zre  = (ushort*)(ws + 20578304);
    ushort* Zim  = (ushort*)(ws + 24838144);

    k_fwd<<<NB * NC, 1024, 0, stream>>>(x, w, XsRe, XsIm, WvRe, WvIm, A4, A5);
    k_gemm<<<WF * NB, 256, 0, stream>>>(XsRe, XsIm, WvRe, WvIm, Zre, Zim);
    k_inv<<<NB * NC, 1024, 0, stream>>>(Zre, Zim, A4, A5, bias, out);
}